// Round 2
// baseline (417.738 us; speedup 1.0000x reference)
//
#include <hip/hip_runtime.h>
#include <hip/hip_cooperative_groups.h>
#include <math.h>

#define B 4
#define H 224
#define W 224
#define C 64
#define K 8
#define WC (W*C)        // 14336
#define HWC (H*W*C)     // 3211264

namespace cg = cooperative_groups;

__device__ inline float wave_reduce_min(float v) {
  #pragma unroll
  for (int off = 32; off > 0; off >>= 1)
    v = fminf(v, __shfl_down(v, off, 64));
  return v;
}
__device__ inline float wave_reduce_max(float v) {
  #pragma unroll
  for (int off = 32; off > 0; off >>= 1)
    v = fmaxf(v, __shfl_down(v, off, 64));
  return v;
}

// ================= FAST PATH =================

// ---- Cooperative producer: float4 column prefix sums, min/max inline ----
// One block per (b,w), 256 threads = 16 h-segments x 16 channel-groups-of-4.
// Each thread holds 14 rows x 4 channels in registers (float4 v4[14]).
// Phase 1: load x (16B/lane), per-thread sums + min/max, block partials.
// grid.sync(). Phase 2: finalize per-sample min/max from 224 L2-hot partials,
// write NORMALIZED prefix as float4. x is read exactly once; P is written
// exactly once; consumer k_main stays byte-identical to the known-good R3.
__global__ __launch_bounds__(256, 4) void k_vpfx_coop(const float* __restrict__ x,
                                                      float* __restrict__ P,
                                                      float* __restrict__ pmin,
                                                      float* __restrict__ pmax) {
  cg::grid_group grid = cg::this_grid();

  int bid = blockIdx.x;           // b*W + w
  int b = bid / W, w = bid % W;
  int seg = threadIdx.x >> 4;     // [0,16) h-segment of 14 rows
  int chg = threadIdx.x & 15;     // [0,16) channel group of 4

  const size_t colbase = (size_t)b*HWC + (size_t)w*C;   // multiple of 4
  const float4* xp4 = (const float4*)(x + colbase);
  const int RS4 = WC / 4;         // float4 row stride = 3584
  const int r0 = seg * 14;

  // --- phase 1: load 14 rows x 4 channels, local sums + min/max ---
  float4 v4[14];
  #pragma unroll
  for (int j = 0; j < 14; ++j) v4[j] = xp4[(size_t)(r0 + j) * RS4 + chg];

  float4 s4 = v4[0];
  float vmin = fminf(fminf(v4[0].x, v4[0].y), fminf(v4[0].z, v4[0].w));
  float vmax = fmaxf(fmaxf(v4[0].x, v4[0].y), fmaxf(v4[0].z, v4[0].w));
  #pragma unroll
  for (int j = 1; j < 14; ++j) {
    s4.x += v4[j].x; s4.y += v4[j].y; s4.z += v4[j].z; s4.w += v4[j].w;
    vmin = fminf(vmin, fminf(fminf(v4[j].x, v4[j].y), fminf(v4[j].z, v4[j].w)));
    vmax = fmaxf(vmax, fmaxf(fmaxf(v4[j].x, v4[j].y), fmaxf(v4[j].z, v4[j].w)));
  }

  __shared__ float4 segsum[16][16];   // [seg][chg]
  __shared__ float smin[4], smax[4];
  segsum[seg][chg] = s4;
  float wmn = wave_reduce_min(vmin), wmx = wave_reduce_max(vmax);
  int wv = threadIdx.x >> 6;
  if ((threadIdx.x & 63) == 0) { smin[wv] = wmn; smax[wv] = wmx; }
  __syncthreads();

  if (threadIdx.x == 0) {
    pmin[bid] = fminf(fminf(smin[0], smin[1]), fminf(smin[2], smin[3]));
    pmax[bid] = fmaxf(fmaxf(smax[0], smax[1]), fmaxf(smax[2], smax[3]));
  }

  // Offset = sum of earlier segments for this channel group (predicated, uniform trip)
  float4 o4 = {0.f, 0.f, 0.f, 0.f};
  #pragma unroll
  for (int ss = 0; ss < 16; ++ss) {
    if (ss < seg) {
      float4 t = segsum[ss][chg];
      o4.x += t.x; o4.y += t.y; o4.z += t.z; o4.w += t.w;
    }
  }

  __threadfence();    // make pmin/pmax visible device-wide (cross-XCD)
  grid.sync();

  // --- phase 2: finalize this sample's min/max (224 partials, L2-hot) ---
  float fmn = INFINITY, fmx = -INFINITY;
  for (int ii = b*W + (int)threadIdx.x; ii < b*W + W; ii += 256) {
    fmn = fminf(fmn, pmin[ii]);
    fmx = fmaxf(fmx, pmax[ii]);
  }
  fmn = wave_reduce_min(fmn);
  fmx = wave_reduce_max(fmx);
  __syncthreads();                 // smin/smax reuse
  if ((threadIdx.x & 63) == 0) { smin[wv] = fmn; smax[wv] = fmx; }
  __syncthreads();
  float xmin = fminf(fminf(smin[0], smin[1]), fminf(smin[2], smin[3]));
  float xmax = fmaxf(fmaxf(smax[0], smax[1]), fmaxf(smax[2], smax[3]));
  float inv  = 1.0f / (xmax - xmin + 1e-6f);

  // --- normalized prefix write (float4) ---
  float4* Pp4 = (float4*)(P + colbase);
  float ax = o4.x, ay = o4.y, az = o4.z, aw = o4.w;
  #pragma unroll
  for (int j = 0; j < 14; ++j) {
    ax += v4[j].x; ay += v4[j].y; az += v4[j].z; aw += v4[j].w;
    float cnt = (float)(r0 + j + 1);
    float sub = cnt * xmin;
    float4 outv;
    outv.x = (ax - sub) * inv;
    outv.y = (ay - sub) * inv;
    outv.z = (az - sub) * inv;
    outv.w = (aw - sub) * inv;
    Pp4[(size_t)(r0 + j) * RS4 + chg] = outv;
  }
}

// ---- Consumer: VERBATIM R3 k_main (known 99-100 us, do not touch) ----
__global__ __launch_bounds__(128) void k_main(
    const float* __restrict__ P, const float* __restrict__ x,
    const float* __restrict__ ols, const float* __restrict__ anchors,
    const float* __restrict__ hwidths, const float* __restrict__ bn_gamma,
    const float* __restrict__ bn_beta, const float* __restrict__ bn_mean,
    const float* __restrict__ bn_var, float* __restrict__ out) {
  int xcd  = blockIdx.x & 7;
  int i    = blockIdx.x >> 3;        // [0,448)
  int rg   = xcd * 112 + (i >> 2);   // global row in [0,896)
  int wave = threadIdx.x >> 6, c = threadIdx.x & 63;
  int chunk = (i & 3) * 2 + wave;    // [0,8)
  int b = rg / H, h = rg % H;
  int w0 = chunk * 28;

  const float LN2 = 0.69314718055994530942f;
  float wg0 = ols[0], wg1 = ols[1], wg2 = ols[2], wg3 = ols[3];
  float l0 = LN2, l1 = 2.f*LN2, l2 = 3.f*LN2, l3 = 4.f*LN2;
  float wsum = wg0 + wg1 + wg2 + wg3;
  float lrbar = (wg0*l0 + wg1*l1 + wg2*l2 + wg3*l3) / wsum;
  float d0 = l0-lrbar, d1 = l1-lrbar, d2 = l2-lrbar, d3 = l3-lrbar;
  float den = wg0*d0*d0 + wg1*d1*d1 + wg2*d2*d2 + wg3*d3*d3;
  float c0 = wg0*d0/den, c1 = wg1*d1/den, c2 = wg2*d2/den, c3 = wg3*d3/den;

  float scl  = bn_gamma[c] * rsqrtf(bn_var[c] + 1e-3f);
  float bofs = bn_beta[c] - bn_mean[c] * scl;
  float anc[K], wd[K];
  #pragma unroll
  for (int k = 0; k < K; ++k) { anc[k] = anchors[c*K + k]; wd[k] = hwidths[c*K + k]; }

  const int hiA[4] = {1, 2, 4, 8};
  const int loA[4] = {0, 1, 3, 7};
  const float* pt[4]; const float* pb[4]; float fb[4];
  #pragma unroll
  for (int s = 0; s < 4; ++s) {
    int ht = h + hiA[s]; if (ht > H-1) ht = H-1;
    int hb = h - loA[s] - 1;
    int hbc = hb < 0 ? 0 : hb;
    pt[s] = P + (size_t)b*HWC + (size_t)ht*WC + c;
    pb[s] = P + (size_t)b*HWC + (size_t)hbc*WC + c;
    fb[s] = hb < 0 ? 0.f : 1.f;
  }

  const float* xrow = x   + (size_t)b*HWC + (size_t)h*WC + c;
  float*       orow = out + (size_t)b*HWC + (size_t)h*WC + c;

  float ring2[2]   = {0,0};
  float ring4[4]   = {0,0,0,0};
  float ring8[8]   = {0,0,0,0,0,0,0,0};
  float ring16[16] = {0,0,0,0,0,0,0,0,0,0,0,0,0,0,0,0};
  float T0 = 0.f, T1 = 0.f, T2 = 0.f, T3 = 0.f;
  float abuf[8] = {0,0,0,0,0,0,0,0};

  for (int t0 = 0; t0 < 48; t0 += 16) {
    #pragma unroll
    for (int u = 0; u < 16; ++u) {
      int t  = t0 + u;
      int wr = w0 - 7 + t;
      float m0 = 0.f, m1 = 0.f, m2 = 0.f, m3 = 0.f;
      if (wr >= 0 && wr < W) {
        int off = wr * C;
        m0 = pt[0][off] - fb[0]*pb[0][off];
        m1 = pt[1][off] - fb[1]*pb[1][off];
        m2 = pt[2][off] - fb[2]*pb[2][off];
        m3 = pt[3][off] - fb[3]*pb[3][off];
      }
      T0 += m0 - ring2[u&1];  ring2[u&1]  = m0;
      T1 += m1 - ring4[u&3];  ring4[u&3]  = m1;
      T2 += m2 - ring8[u&7];  ring8[u&7]  = m2;
      T3 += m3 - ring16[u];   ring16[u]   = m3;
      abuf[(u+7)&7] += c0 * __logf(fmaxf(T0, 0.f) + 1e-6f);
      abuf[(u+6)&7] += c1 * __logf(fmaxf(T1, 0.f) + 1e-6f);
      abuf[(u+4)&7] += c2 * __logf(fmaxf(T2, 0.f) + 1e-6f);
      abuf[u&7]     += c3 * __logf(fmaxf(T3, 0.f) + 1e-6f);
      int ig = w0 - 15 + t;
      if (t >= 15 && ig <= w0 + 27) {
        float alpha = abuf[u&7];
        float a = alpha * scl + bofs;
        float sc = 0.f;
        #pragma unroll
        for (int k = 0; k < K; ++k)
          sc += fmaxf(0.f, 1.f - wd[k]*fabsf(a - anc[k]));
        float sig = 1.f / (1.f + __expf(-sc));
        float xv = __builtin_nontemporal_load(&xrow[ig*C]);
        __builtin_nontemporal_store(xv + sig, &orow[ig*C]);
      }
      abuf[u&7] = 0.f;
    }
  }
}

// ================= FALLBACK PATH (verbatim R0 pipeline) =================

__global__ __launch_bounds__(256) void k_minmax_part(const float* __restrict__ x,
                                                     float* __restrict__ scratch) {
  int s   = blockIdx.x >> 9;
  int blk = blockIdx.x & 511;
  const float4* xs = (const float4*)(x + (size_t)s * HWC);
  const int n4 = HWC / 4;
  float vmin = INFINITY, vmax = -INFINITY;
  for (int i = blk*256 + threadIdx.x; i < n4; i += 512*256) {
    float4 v = xs[i];
    vmin = fminf(vmin, fminf(fminf(v.x, v.y), fminf(v.z, v.w)));
    vmax = fmaxf(vmax, fmaxf(fmaxf(v.x, v.y), fmaxf(v.z, v.w)));
  }
  __shared__ float smin[4], smax[4];
  float wmin = wave_reduce_min(vmin), wmax = wave_reduce_max(vmax);
  int wave = threadIdx.x >> 6, lane = threadIdx.x & 63;
  if (lane == 0) { smin[wave] = wmin; smax[wave] = wmax; }
  __syncthreads();
  if (threadIdx.x == 0) {
    float m = fminf(fminf(smin[0], smin[1]), fminf(smin[2], smin[3]));
    float M = fmaxf(fmaxf(smax[0], smax[1]), fmaxf(smax[2], smax[3]));
    scratch[blockIdx.x]        = m;
    scratch[2048 + blockIdx.x] = M;
  }
}

__global__ __launch_bounds__(256) void k_vpfx(const float* __restrict__ x,
                                              const float* __restrict__ scratch,
                                              float* __restrict__ P) {
  int bid = blockIdx.x;
  int b = bid / W, w = bid % W;
  int q = threadIdx.x >> 6, c = threadIdx.x & 63;

  float vmin = fminf(scratch[b*512 + threadIdx.x], scratch[b*512 + 256 + threadIdx.x] - 0.f);
  float vmax = fmaxf(scratch[2048 + b*512 + threadIdx.x], scratch[2048 + b*512 + 256 + threadIdx.x]);
  __shared__ float smin[4], smax[4];
  float wmin = wave_reduce_min(vmin), wmax = wave_reduce_max(vmax);
  if ((threadIdx.x & 63) == 0) { smin[q] = wmin; smax[q] = wmax; }
  __syncthreads();
  float xmin = fminf(fminf(smin[0], smin[1]), fminf(smin[2], smin[3]));
  float xmax = fmaxf(fmaxf(smax[0], smax[1]), fmaxf(smax[2], smax[3]));
  float inv  = 1.0f / (xmax - xmin + 1e-6f);

  size_t colbase = (size_t)b*HWC + (size_t)w*C + c;
  const int hq = q * 56;
  const float* xp = x + colbase + (size_t)hq * WC;

  float v[56];
  #pragma unroll
  for (int j = 0; j < 56; ++j) v[j] = xp[(size_t)j * WC];
  float sum = 0.f;
  #pragma unroll
  for (int j = 0; j < 56; ++j) sum += v[j];

  __shared__ float lds[256];
  lds[threadIdx.x] = sum;
  __syncthreads();

  float acc = 0.f;
  for (int qq = 0; qq < q; ++qq) acc += lds[qq*64 + c];

  float* Pp = P + colbase + (size_t)hq * WC;
  #pragma unroll
  for (int j = 0; j < 56; ++j) {
    acc += v[j];
    Pp[(size_t)j * WC] = (acc - (float)(hq + j + 1) * xmin) * inv;
  }
}

// ================================ host ================================

extern "C" void kernel_launch(void* const* d_in, const int* in_sizes, int n_in,
                              void* d_out, int out_size, void* d_ws, size_t ws_size,
                              hipStream_t stream) {
  const float* x        = (const float*)d_in[0];
  const float* ols      = (const float*)d_in[1];
  const float* anchors  = (const float*)d_in[2];
  const float* hwidths  = (const float*)d_in[3];
  const float* bn_gamma = (const float*)d_in[4];
  const float* bn_beta  = (const float*)d_in[5];
  const float* bn_mean  = (const float*)d_in[6];
  const float* bn_var   = (const float*)d_in[7];
  float* out = (float*)d_out;
  float* P   = (float*)d_ws;                      // B*H*W*C floats = 51.4 MB
  const size_t PBYTES = (size_t)B * HWC * sizeof(float);

  bool done = false;
  if (ws_size >= PBYTES + 8192) {
    float* pmn = (float*)((char*)d_ws + PBYTES);  // 896 used, 1024 reserved
    float* pmx = pmn + 1024;
    void* args[] = { (void*)&x, (void*)&P, (void*)&pmn, (void*)&pmx };
    hipError_t err = hipLaunchCooperativeKernel((const void*)k_vpfx_coop,
                                                dim3(B*W), dim3(256),
                                                args, 0, stream);
    if (err == hipSuccess) {
      hipLaunchKernelGGL(k_main, dim3(B*H*4), dim3(128), 0, stream,
                         P, x, ols, anchors, hwidths,
                         bn_gamma, bn_beta, bn_mean, bn_var, out);
      done = true;
    }
  }
  if (!done) {
    // fallback: verbatim R0 3-kernel pipeline (scratch in d_out)
    float* scratch = out;
    hipLaunchKernelGGL(k_minmax_part, dim3(2048),  dim3(256), 0, stream, x, scratch);
    hipLaunchKernelGGL(k_vpfx,        dim3(B*W),   dim3(256), 0, stream, x, scratch, P);
    hipLaunchKernelGGL(k_main,        dim3(B*H*4), dim3(128), 0, stream,
                       P, x, ols, anchors, hwidths,
                       bn_gamma, bn_beta, bn_mean, bn_var, out);
  }
}

// Round 3
// 214.071 us; speedup vs baseline: 1.9514x; 1.9514x over previous
//
#include <hip/hip_runtime.h>
#include <math.h>

#define B 4
#define H 224
#define W 224
#define C 64
#define K 8
#define WC (W*C)        // 14336
#define HWC (H*W*C)     // 3211264

__device__ inline float wave_reduce_min(float v) {
  #pragma unroll
  for (int off = 32; off > 0; off >>= 1)
    v = fminf(v, __shfl_down(v, off, 64));
  return v;
}
__device__ inline float wave_reduce_max(float v) {
  #pragma unroll
  for (int off = 32; off > 0; off >>= 1)
    v = fmaxf(v, __shfl_down(v, off, 64));
  return v;
}

// ---------------- Kernel 0: per-block partial min/max per sample ----------------
// scratch (in d_out, consumed by k_vpfx4 before k_main overwrites d_out):
//   [0..2047] per-block mins (sample*512 + blk), [2048..4095] per-block maxs
__global__ __launch_bounds__(256) void k_minmax_part(const float* __restrict__ x,
                                                     float* __restrict__ scratch) {
  int s   = blockIdx.x >> 9;      // 512 blocks per sample
  int blk = blockIdx.x & 511;
  const float4* xs = (const float4*)(x + (size_t)s * HWC);
  const int n4 = HWC / 4;         // 802816
  float vmin = INFINITY, vmax = -INFINITY;
  for (int i = blk*256 + threadIdx.x; i < n4; i += 512*256) {
    float4 v = xs[i];
    vmin = fminf(vmin, fminf(fminf(v.x, v.y), fminf(v.z, v.w)));
    vmax = fmaxf(vmax, fmaxf(fmaxf(v.x, v.y), fmaxf(v.z, v.w)));
  }
  __shared__ float smin[4], smax[4];
  float wmin = wave_reduce_min(vmin), wmax = wave_reduce_max(vmax);
  int wave = threadIdx.x >> 6, lane = threadIdx.x & 63;
  if (lane == 0) { smin[wave] = wmin; smax[wave] = wmax; }
  __syncthreads();
  if (threadIdx.x == 0) {
    float m = fminf(fminf(smin[0], smin[1]), fminf(smin[2], smin[3]));
    float M = fmaxf(fmaxf(smax[0], smax[1]), fmaxf(smax[2], smax[3]));
    scratch[blockIdx.x]        = m;
    scratch[2048 + blockIdx.x] = M;
  }
}

// ---------------- Kernel 1: float4 column prefix sums into P ----------------
// One block per (b,w), 256 threads = 16 h-segments x 16 channel-groups-of-4.
// Each thread holds 14 rows x 4 channels in registers (16B/lane loads+stores
// -- the G13 fix for the 106us scalar k_vpfx). Preamble redundantly reduces
// the sample's 512 min/max partials (R0-proven, no extra dispatch).
// Math verified correct in R2's coop kernel (passed, same absmax).
__global__ __launch_bounds__(256) void k_vpfx4(const float* __restrict__ x,
                                               const float* __restrict__ scratch,
                                               float* __restrict__ P) {
  int bid = blockIdx.x;           // b*W + w
  int b = bid / W, w = bid % W;
  int seg = threadIdx.x >> 4;     // [0,16) h-segment of 14 rows
  int chg = threadIdx.x & 15;     // [0,16) channel group of 4
  int wv  = threadIdx.x >> 6;

  // --- preamble: finalize this sample's min/max from 512 partials (L2-hot) ---
  float vmn = fminf(scratch[b*512 + threadIdx.x], scratch[b*512 + 256 + threadIdx.x]);
  float vmx = fmaxf(scratch[2048 + b*512 + threadIdx.x], scratch[2048 + b*512 + 256 + threadIdx.x]);
  __shared__ float smin[4], smax[4];
  float wmn = wave_reduce_min(vmn), wmx = wave_reduce_max(vmx);
  if ((threadIdx.x & 63) == 0) { smin[wv] = wmn; smax[wv] = wmx; }
  __syncthreads();
  float xmin = fminf(fminf(smin[0], smin[1]), fminf(smin[2], smin[3]));
  float xmax = fmaxf(fmaxf(smax[0], smax[1]), fmaxf(smax[2], smax[3]));
  float inv  = 1.0f / (xmax - xmin + 1e-6f);

  const size_t colbase = (size_t)b*HWC + (size_t)w*C;   // multiple of 4
  const float4* xp4 = (const float4*)(x + colbase);
  const int RS4 = WC / 4;         // float4 row stride = 3584
  const int r0 = seg * 14;

  // --- load 14 rows x 4 channels, per-thread segment sums ---
  float4 v4[14];
  #pragma unroll
  for (int j = 0; j < 14; ++j) v4[j] = xp4[(size_t)(r0 + j) * RS4 + chg];

  float4 s4 = v4[0];
  #pragma unroll
  for (int j = 1; j < 14; ++j) {
    s4.x += v4[j].x; s4.y += v4[j].y; s4.z += v4[j].z; s4.w += v4[j].w;
  }

  __shared__ float4 segsum[16][16];   // [seg][chg]
  segsum[seg][chg] = s4;
  __syncthreads();

  // Offset = sum of earlier segments for this channel group (broadcast reads)
  float4 o4 = {0.f, 0.f, 0.f, 0.f};
  #pragma unroll
  for (int ss = 0; ss < 16; ++ss) {
    if (ss < seg) {
      float4 t = segsum[ss][chg];
      o4.x += t.x; o4.y += t.y; o4.z += t.z; o4.w += t.w;
    }
  }

  // --- normalized prefix write (float4) ---
  float4* Pp4 = (float4*)(P + colbase);
  float ax = o4.x, ay = o4.y, az = o4.z, aw = o4.w;
  #pragma unroll
  for (int j = 0; j < 14; ++j) {
    ax += v4[j].x; ay += v4[j].y; az += v4[j].z; aw += v4[j].w;
    float sub = (float)(r0 + j + 1) * xmin;
    float4 outv;
    outv.x = (ax - sub) * inv;
    outv.y = (ay - sub) * inv;
    outv.z = (az - sub) * inv;
    outv.w = (aw - sub) * inv;
    Pp4[(size_t)(r0 + j) * RS4 + chg] = outv;
  }
}

// ---------------- Kernel 2: VERBATIM R3 k_main (known 99-100 us, do not touch) --
__global__ __launch_bounds__(128) void k_main(
    const float* __restrict__ P, const float* __restrict__ x,
    const float* __restrict__ ols, const float* __restrict__ anchors,
    const float* __restrict__ hwidths, const float* __restrict__ bn_gamma,
    const float* __restrict__ bn_beta, const float* __restrict__ bn_mean,
    const float* __restrict__ bn_var, float* __restrict__ out) {
  int xcd  = blockIdx.x & 7;
  int i    = blockIdx.x >> 3;        // [0,448)
  int rg   = xcd * 112 + (i >> 2);   // global row in [0,896)
  int wave = threadIdx.x >> 6, c = threadIdx.x & 63;
  int chunk = (i & 3) * 2 + wave;    // [0,8)
  int b = rg / H, h = rg % H;
  int w0 = chunk * 28;

  const float LN2 = 0.69314718055994530942f;
  float wg0 = ols[0], wg1 = ols[1], wg2 = ols[2], wg3 = ols[3];
  float l0 = LN2, l1 = 2.f*LN2, l2 = 3.f*LN2, l3 = 4.f*LN2;
  float wsum = wg0 + wg1 + wg2 + wg3;
  float lrbar = (wg0*l0 + wg1*l1 + wg2*l2 + wg3*l3) / wsum;
  float d0 = l0-lrbar, d1 = l1-lrbar, d2 = l2-lrbar, d3 = l3-lrbar;
  float den = wg0*d0*d0 + wg1*d1*d1 + wg2*d2*d2 + wg3*d3*d3;
  float c0 = wg0*d0/den, c1 = wg1*d1/den, c2 = wg2*d2/den, c3 = wg3*d3/den;

  float scl  = bn_gamma[c] * rsqrtf(bn_var[c] + 1e-3f);
  float bofs = bn_beta[c] - bn_mean[c] * scl;
  float anc[K], wd[K];
  #pragma unroll
  for (int k = 0; k < K; ++k) { anc[k] = anchors[c*K + k]; wd[k] = hwidths[c*K + k]; }

  const int hiA[4] = {1, 2, 4, 8};
  const int loA[4] = {0, 1, 3, 7};
  const float* pt[4]; const float* pb[4]; float fb[4];
  #pragma unroll
  for (int s = 0; s < 4; ++s) {
    int ht = h + hiA[s]; if (ht > H-1) ht = H-1;
    int hb = h - loA[s] - 1;
    int hbc = hb < 0 ? 0 : hb;
    pt[s] = P + (size_t)b*HWC + (size_t)ht*WC + c;
    pb[s] = P + (size_t)b*HWC + (size_t)hbc*WC + c;
    fb[s] = hb < 0 ? 0.f : 1.f;
  }

  const float* xrow = x   + (size_t)b*HWC + (size_t)h*WC + c;
  float*       orow = out + (size_t)b*HWC + (size_t)h*WC + c;

  float ring2[2]   = {0,0};
  float ring4[4]   = {0,0,0,0};
  float ring8[8]   = {0,0,0,0,0,0,0,0};
  float ring16[16] = {0,0,0,0,0,0,0,0,0,0,0,0,0,0,0,0};
  float T0 = 0.f, T1 = 0.f, T2 = 0.f, T3 = 0.f;
  float abuf[8] = {0,0,0,0,0,0,0,0};

  for (int t0 = 0; t0 < 48; t0 += 16) {
    #pragma unroll
    for (int u = 0; u < 16; ++u) {
      int t  = t0 + u;
      int wr = w0 - 7 + t;
      float m0 = 0.f, m1 = 0.f, m2 = 0.f, m3 = 0.f;
      if (wr >= 0 && wr < W) {
        int off = wr * C;
        m0 = pt[0][off] - fb[0]*pb[0][off];
        m1 = pt[1][off] - fb[1]*pb[1][off];
        m2 = pt[2][off] - fb[2]*pb[2][off];
        m3 = pt[3][off] - fb[3]*pb[3][off];
      }
      T0 += m0 - ring2[u&1];  ring2[u&1]  = m0;
      T1 += m1 - ring4[u&3];  ring4[u&3]  = m1;
      T2 += m2 - ring8[u&7];  ring8[u&7]  = m2;
      T3 += m3 - ring16[u];   ring16[u]   = m3;
      abuf[(u+7)&7] += c0 * __logf(fmaxf(T0, 0.f) + 1e-6f);
      abuf[(u+6)&7] += c1 * __logf(fmaxf(T1, 0.f) + 1e-6f);
      abuf[(u+4)&7] += c2 * __logf(fmaxf(T2, 0.f) + 1e-6f);
      abuf[u&7]     += c3 * __logf(fmaxf(T3, 0.f) + 1e-6f);
      int ig = w0 - 15 + t;
      if (t >= 15 && ig <= w0 + 27) {
        float alpha = abuf[u&7];
        float a = alpha * scl + bofs;
        float sc = 0.f;
        #pragma unroll
        for (int k = 0; k < K; ++k)
          sc += fmaxf(0.f, 1.f - wd[k]*fabsf(a - anc[k]));
        float sig = 1.f / (1.f + __expf(-sc));
        float xv = __builtin_nontemporal_load(&xrow[ig*C]);
        __builtin_nontemporal_store(xv + sig, &orow[ig*C]);
      }
      abuf[u&7] = 0.f;
    }
  }
}

// ================================ host ================================

extern "C" void kernel_launch(void* const* d_in, const int* in_sizes, int n_in,
                              void* d_out, int out_size, void* d_ws, size_t ws_size,
                              hipStream_t stream) {
  const float* x        = (const float*)d_in[0];
  const float* ols      = (const float*)d_in[1];
  const float* anchors  = (const float*)d_in[2];
  const float* hwidths  = (const float*)d_in[3];
  const float* bn_gamma = (const float*)d_in[4];
  const float* bn_beta  = (const float*)d_in[5];
  const float* bn_mean  = (const float*)d_in[6];
  const float* bn_var   = (const float*)d_in[7];
  float* out = (float*)d_out;
  float* P   = (float*)d_ws;       // B*H*W*C floats = 51.4 MB
  float* scratch = out;            // d_out doubles as min/max scratch (consumed by
                                   // k_vpfx4 before k_main overwrites d_out)

  hipLaunchKernelGGL(k_minmax_part, dim3(2048),  dim3(256), 0, stream, x, scratch);
  hipLaunchKernelGGL(k_vpfx4,       dim3(B*W),   dim3(256), 0, stream, x, scratch, P);
  hipLaunchKernelGGL(k_main,        dim3(B*H*4), dim3(128), 0, stream,
                     P, x, ols, anchors, hwidths, bn_gamma, bn_beta, bn_mean, bn_var, out);
}